// Round 10
// baseline (174.346 us; speedup 1.0000x reference)
//
#include <hip/hip_runtime.h>

// ============================================================================
// ROUND 10 = MEASUREMENT ROUND. Identical to round 9 except bucket_own is
// launched 3x (it is effect-idempotent: deterministic span layout, len
// always overwritten, slots beyond len never read). Purpose:
//   (1) dur_us delta = 2 x bucket cost -> resolves the fill-in/out-of-dur
//       ambiguity that has defeated 5 bottom-up theories;
//   (2) three ~equal dispatches displace the 41-44us fills from top-5,
//       giving bucket_own's first-ever direct rocprof row (FETCH/WRITE/
//       VALUBusy/Occupancy) to pick the round-11 fix.
// ============================================================================

#define N_NODES 100000
#define N_EDGES 1600000
#define IN_CH 8
#define HID_CH 64
#define OUT_CH 2

// 1024 dst-ranges of 98 nodes (1024*98 = 100352 >= 100000).
#define R2   1024
#define RN   98
#define CAP  1920    // per-range total capacity; Binom mean 1568, sd ~40 -> +8.9σ

#define NCHUNK 32
#define CH_E (N_EDGES / NCHUNK)   // 50000 edges per chunk (25000 int2)
#define NW   16                   // waves per 1024-thread block
#define WSTG 552                  // per-wave staging cap: mean 390, sd 18.5, +8.7σ
#define SPANCAP 128               // ints per (range,chunk) span
#define SLOTS (NCHUNK * SPANCAP)  // 4096 ints per range

// ---- workspace (4-byte words), ~26 MB ----
#define WS_CSR    (R2 * SLOTS)
#define WS_OFFDEG (WS_CSR + R2 * CAP)
#define WS_G      (WS_OFFDEG + R2 * RN)

// chunk = blockIdx&31, own = blockIdx>>5 (8 owners of chunk c all == c mod 8
// -> same XCD; chunk L2/L3-served after first scan).
__global__ __launch_bounds__(1024) void bucket_own(
        const int* __restrict__ src, const int* __restrict__ dst,
        int* __restrict__ bucket) {
    __shared__ int stg[NW * WSTG];   // staged owned edges, per-wave regions
    __shared__ int wcnt[NW];
    __shared__ int cur[R2];          // block-local span fill counters
    int tid = threadIdx.x;
    int w = tid >> 6;
    unsigned own = blockIdx.x >> 5;
    int chunk = blockIdx.x & 31;
    if (tid < R2) cur[tid] = 0;
    if (tid < NW) wcnt[tid] = 0;
    __syncthreads();

    const int2* d2 = (const int2*)(dst + (size_t)chunk * CH_E);
    const int2* s2 = (const int2*)(src + (size_t)chunk * CH_E);
    int* mystg = stg + w * WSTG;
    for (int i = tid; i < CH_E / 2; i += 1024) {
        int2 d = d2[i];
        int2 s = s2[i];
        {
            unsigned r = (unsigned)d.x / RN;
            if ((r & 7) == own) {
                unsigned dl = (unsigned)d.x - r * RN;
                int p = atomicAdd(&wcnt[w], 1);   // wave-local LDS counter
                if (p < WSTG)
                    mystg[p] = (int)(((r >> 3) << 24) | (dl << 17) | (unsigned)s.x);
            }
        }
        {
            unsigned r = (unsigned)d.y / RN;
            if ((r & 7) == own) {
                unsigned dl = (unsigned)d.y - r * RN;
                int p = atomicAdd(&wcnt[w], 1);
                if (p < WSTG)
                    mystg[p] = (int)(((r >> 3) << 24) | (dl << 17) | (unsigned)s.y);
            }
        }
    }
    __syncthreads();

    // Place into fixed spans: LDS rtn atomic + single-writer line-aligned store.
    int mycnt = wcnt[w];
    if (mycnt > WSTG) mycnt = WSTG;
    for (int j = tid & 63; j < mycnt; j += 64) {
        int e = mystg[j];
        unsigned r = (((unsigned)e >> 24) << 3) | own;
        int slot = atomicAdd(&cur[r], 1);
        if (slot < SPANCAP - 1)
            bucket[(size_t)(r * NCHUNK + chunk) * SPANCAP + 1 + slot] = e & 0x00FFFFFF;
    }
    __syncthreads();

    // Write span lengths (slot0) for ALL owned ranges, including empty ones.
    for (int i = tid; i < R2; i += 1024) {
        if (((unsigned)i & 7) == own) {
            int c = cur[i];
            if (c > SPANCAP - 1) c = SPANCAP - 1;
            bucket[(size_t)(i * NCHUNK + chunk) * SPANCAP] = c;
        }
    }
}

// Layer 1 (proven sorted structure): load the range's 32 spans (16KB,
// coalesced), LDS counting-sort to node order (guarded by per-span len),
// 4-lane-per-node walk + distributed MLP. Dumps compact sorted CSR + offdeg.
__global__ __launch_bounds__(512) void sage1_range(
        const int* __restrict__ bucket,
        const float* __restrict__ x,
        const float* __restrict__ W_l1, const float* __restrict__ b_l1,
        const float* __restrict__ W_r1,
        const float* __restrict__ W_l2, const float* __restrict__ b_l2,
        const float* __restrict__ W_r2,
        int* __restrict__ csr, int* __restrict__ offdeg,
        float* __restrict__ g, float* __restrict__ out_rt) {
    __shared__ int raw[SLOTS];   // 16KB: 32 spans of 128 (slot0 = len)
    __shared__ int seg[CAP];
    __shared__ int scnt[128];
    __shared__ int soff[128];
    __shared__ int scur[128];
    __shared__ int wtot[2];
    __shared__ float sWl[HID_CH * IN_CH];
    __shared__ float sWr[HID_CH * IN_CH];
    __shared__ float sb[HID_CH];
    __shared__ float sWl2[OUT_CH * HID_CH];
    __shared__ float sWr2[OUT_CH * HID_CH];
    __shared__ float sb2[OUT_CH];

    int tid = threadIdx.x;
    for (int i = tid; i < HID_CH * IN_CH; i += 512) {
        sWl[i] = W_l1[i];
        sWr[i] = W_r1[i];
    }
    for (int i = tid; i < HID_CH; i += 512) sb[i] = b_l1[i];
    for (int i = tid; i < OUT_CH * HID_CH; i += 512) {
        sWl2[i] = W_l2[i];
        sWr2[i] = W_r2[i];
    }
    if (tid < OUT_CH) sb2[tid] = b_l2[tid];
    if (tid < 128) scnt[tid] = 0;

    int r = blockIdx.x;
    const int* bin = bucket + (size_t)r * SLOTS;
    for (int j = tid; j < SLOTS; j += 512) raw[j] = bin[j];
    __syncthreads();

    // Histogram by node (guard: slot 1..len within each 128-int span).
    for (int j = tid; j < SLOTS; j += 512) {
        int sl = j & (SPANCAP - 1);
        int len = raw[j & ~(SPANCAP - 1)];   // slot0 of this span (LDS broadcast)
        if (sl >= 1 && sl <= len) atomicAdd(&scnt[raw[j] >> 17], 1);
    }
    __syncthreads();

    // Exclusive scan over 128 slots (RN=98 padded): per-wave shfl scan, 2 waves.
    int lane = tid & 63;
    if (tid < 128) {
        int v = scnt[tid];
        int incl = v;
        #pragma unroll
        for (int d = 1; d < 64; d <<= 1) {
            int t2 = __shfl_up(incl, d);
            if (lane >= d) incl += t2;
        }
        if (lane == 63) wtot[tid >> 6] = incl;
        soff[tid] = incl - v;
    }
    __syncthreads();
    if (tid < 128) {
        int o = soff[tid] + ((tid >= 64) ? wtot[0] : 0);
        soff[tid] = o;
        scur[tid] = o;
    }
    __syncthreads();

    // Scatter to node-sorted compact seg[].
    for (int j = tid; j < SLOTS; j += 512) {
        int sl = j & (SPANCAP - 1);
        int len = raw[j & ~(SPANCAP - 1)];
        if (sl >= 1 && sl <= len) {
            int w = raw[j];
            int p = atomicAdd(&scur[w >> 17], 1);
            seg[p] = w & 0x1FFFF;
        }
    }
    __syncthreads();

    // Dump compact node-sorted CSR (coalesced) for the layer-2 walk.
    int total = wtot[0] + wtot[1];
    if (total > CAP) total = CAP;
    int* cw = csr + (size_t)r * CAP;
    for (int j = tid; j < total; j += 512) cw[j] = seg[j];

    // Walk: 4 lanes per node, independent (pipelineable) LDS + global loads.
    int q = tid >> 2;
    int l = tid & 3;
    int node = r * RN + q;
    if (q < RN && node < N_NODES) {
        int o = soff[q];
        int dn = scnt[q];
        if (l == 0) offdeg[node] = o | (dn << 16);

        float acc[IN_CH];
        #pragma unroll
        for (int c = 0; c < IN_CH; c++) acc[c] = 0.0f;
        for (int j = o + l; j < o + dn; j += 4) {
            int s = seg[j];
            const float4* xs = (const float4*)(x + (size_t)s * IN_CH);
            float4 a = xs[0];
            float4 b = xs[1];
            acc[0] += a.x; acc[1] += a.y; acc[2] += a.z; acc[3] += a.w;
            acc[4] += b.x; acc[5] += b.y; acc[6] += b.z; acc[7] += b.w;
        }
        #pragma unroll
        for (int c = 0; c < IN_CH; c++) {
            acc[c] += __shfl_xor(acc[c], 1);
            acc[c] += __shfl_xor(acc[c], 2);
        }
        float inv = 1.0f / fmaxf((float)dn, 1.0f);
        float ag[IN_CH], xa[IN_CH];
        #pragma unroll
        for (int c = 0; c < IN_CH; c++) ag[c] = acc[c] * inv;
        const float4* xp = (const float4*)(x + (size_t)node * IN_CH);
        float4 x0 = xp[0], x1 = xp[1];
        xa[0] = x0.x; xa[1] = x0.y; xa[2] = x0.z; xa[3] = x0.w;
        xa[4] = x1.x; xa[5] = x1.y; xa[6] = x1.z; xa[7] = x1.w;

        // Distributed MLP: lane l handles hidden units [16l, 16l+16).
        float g0 = 0.f, g1 = 0.f, r0 = 0.f, r1 = 0.f;
        int k0 = l * 16;
        #pragma unroll 4
        for (int kk = k0; kk < k0 + 16; kk++) {
            float hk = sb[kk];
            #pragma unroll
            for (int c = 0; c < IN_CH; c++) {
                hk += sWl[kk * IN_CH + c] * ag[c];
                hk += sWr[kk * IN_CH + c] * xa[c];
            }
            hk = fmaxf(hk, 0.0f);   // ReLU (dropout identity in eval)
            g0 += sWl2[kk] * hk;
            g1 += sWl2[HID_CH + kk] * hk;
            r0 += sWr2[kk] * hk;
            r1 += sWr2[HID_CH + kk] * hk;
        }
        g0 += __shfl_xor(g0, 1); g0 += __shfl_xor(g0, 2);
        g1 += __shfl_xor(g1, 1); g1 += __shfl_xor(g1, 2);
        r0 += __shfl_xor(r0, 1); r0 += __shfl_xor(r0, 2);
        r1 += __shfl_xor(r1, 1); r1 += __shfl_xor(r1, 2);
        if (l == 0) {
            g[(size_t)node * 2 + 0] = g0;
            g[(size_t)node * 2 + 1] = g1;
            float2 rt;
            rt.x = r0 + sb2[0];
            rt.y = r1 + sb2[1];
            *(float2*)(out_rt + (size_t)node * 2) = rt;
        }
    }
}

// Layer 2 (round-0 walk): 4 lanes/node read the node's contiguous CSR span,
// gather g[src], shfl-reduce; out = sum/max(dn,1) + rt.
__global__ __launch_bounds__(256) void sage2_kernel(
        const int* __restrict__ csr, const int* __restrict__ offdeg,
        const float* __restrict__ g, float* __restrict__ out) {
    int t = blockIdx.x * blockDim.x + threadIdx.x;
    int node = t >> 2;
    int l = t & 3;
    if (node >= N_NODES) return;
    int r = node / RN;
    int od = offdeg[node];
    int o = od & 0xFFFF;
    int dn = od >> 16;
    const int* seg = csr + (size_t)r * CAP;
    float a0 = 0.f, a1 = 0.f;
    for (int j = o + l; j < o + dn; j += 4) {
        int s = seg[j];
        float2 gv = *(const float2*)(g + (size_t)s * 2);
        a0 += gv.x;
        a1 += gv.y;
    }
    a0 += __shfl_xor(a0, 1); a0 += __shfl_xor(a0, 2);
    a1 += __shfl_xor(a1, 1); a1 += __shfl_xor(a1, 2);
    if (l == 0) {
        float inv = 1.0f / fmaxf((float)dn, 1.0f);
        float2 rt = *(const float2*)(out + (size_t)node * 2);
        float2 ov;
        ov.x = a0 * inv + rt.x;
        ov.y = a1 * inv + rt.y;
        *(float2*)(out + (size_t)node * 2) = ov;
    }
}

extern "C" void kernel_launch(void* const* d_in, const int* in_sizes, int n_in,
                              void* d_out, int out_size, void* d_ws, size_t ws_size,
                              hipStream_t stream) {
    const float* x    = (const float*)d_in[0];
    const int*   ei   = (const int*)d_in[1];   // [2, N_EDGES] int32 per harness
    const float* W_l1 = (const float*)d_in[2];
    const float* b_l1 = (const float*)d_in[3];
    const float* W_r1 = (const float*)d_in[4];
    const float* W_l2 = (const float*)d_in[5];
    const float* b_l2 = (const float*)d_in[6];
    const float* W_r2 = (const float*)d_in[7];
    float* out = (float*)d_out;

    const int* src = ei;
    const int* dst = ei + N_EDGES;

    int*   bucket = (int*)d_ws;
    int*   csr    = (int*)d_ws + WS_CSR;
    int*   offdeg = (int*)d_ws + WS_OFFDEG;
    float* g      = (float*)d_ws + WS_G;

    // MEASUREMENT: bucket_own x3 (idempotent). dur delta vs round 9 = 2x its
    // cost; three equal dispatches surface its rocprof counters in top-5.
    bucket_own<<<NCHUNK * 8, 1024, 0, stream>>>(src, dst, bucket);
    bucket_own<<<NCHUNK * 8, 1024, 0, stream>>>(src, dst, bucket);
    bucket_own<<<NCHUNK * 8, 1024, 0, stream>>>(src, dst, bucket);
    sage1_range<<<R2, 512, 0, stream>>>(bucket, x,
                                        W_l1, b_l1, W_r1, W_l2, b_l2, W_r2,
                                        csr, offdeg, g, out);
    sage2_kernel<<<(4 * N_NODES + 255) / 256, 256, 0, stream>>>(csr, offdeg, g, out);
}

// Round 11
// 138.475 us; speedup vs baseline: 1.2590x; 1.2590x over previous
//
#include <hip/hip_runtime.h>

#define N_NODES 100000
#define N_EDGES 1600000
#define IN_CH 8
#define HID_CH 64
#define OUT_CH 2

// 1024 dst-ranges of 98 nodes (1024*98 = 100352 >= 100000).
#define R2   1024
#define RN   98
#define CAP  1920    // per-range capacity; Binom mean 1568, sd ~40 -> +8.9σ
#define CSTRIDE 16   // cursor padded to one range per 64B line

// Round-11 binning: 128 blocks, each owns a DISTINCT 12.5K-edge chunk
// (1x edge reads — R10 measured bucket_own's 17us == its 8x redundant scan,
// 102MB/6.3TBps = 16.2us). Within a block: LDS histogram -> 1024-wide scan ->
// global cursor reservation -> second (L2/L3-hot) pass placing edges
// range-sorted into an LDS stage -> per-wave coalesced dump of ~12-int
// contiguous spans (~full-line, near-single-writer writes).
#define NB   128
#define CH   (N_EDGES / NB)   // 12500 edges per chunk
#define CH2  (CH / 2)         // 6250 int2

// ---- workspace (4-byte words), ~9 MB ----
//   cursor : R2*CSTRIDE @ 0          (memset 0; per-range fill count, padded)
//   bucket : R2*CAP     @ WS_BUCKET  (packed (dl<<17)|src; csr overwrites in place)
//   offdeg : R2*RN      @ WS_OFFDEG  (per node: off | deg<<16, range-local)
//   g      : N*2 float  @ WS_G       (W_l2 @ h per node)
#define WS_BUCKET (R2 * CSTRIDE)
#define WS_OFFDEG (WS_BUCKET + R2 * CAP)
#define WS_G      (WS_OFFDEG + R2 * RN)

__global__ __launch_bounds__(1024) void bucket_sort(
        const int* __restrict__ src, const int* __restrict__ dst,
        int* __restrict__ cursor, int* __restrict__ bucket) {
    __shared__ int stage[CH];    // 50KB: chunk's edges, range-sorted (exact fit)
    __shared__ int cnt[R2];      // per-range count within this chunk
    __shared__ int loc[R2];      // local exclusive offsets (dump base)
    __shared__ int lcur[R2];     // placement cursors
    __shared__ int base[R2];     // reserved global span base
    __shared__ int wsum[16];
    int tid = threadIdx.x;       // 1024 threads == R2: no loops over ranges
    int w = tid >> 6;
    int lane = tid & 63;

    cnt[tid] = 0;
    __syncthreads();

    const int2* dch = (const int2*)(dst + (size_t)blockIdx.x * CH);
    const int2* sch = (const int2*)(src + (size_t)blockIdx.x * CH);

    // Pass 1: histogram over ranges.
    for (int i = tid; i < CH2; i += 1024) {
        int2 d = dch[i];
        atomicAdd(&cnt[(unsigned)d.x / RN], 1);
        atomicAdd(&cnt[(unsigned)d.y / RN], 1);
    }
    __syncthreads();

    // 1024-entry exclusive scan: per-wave shfl scan + wave-total scan.
    int v = cnt[tid];
    int incl = v;
    #pragma unroll
    for (int dd = 1; dd < 64; dd <<= 1) {
        int t2 = __shfl_up(incl, dd);
        if (lane >= dd) incl += t2;
    }
    if (lane == 63) wsum[w] = incl;
    loc[tid] = incl - v;
    __syncthreads();
    if (w == 0 && lane < 16) {
        int s = wsum[lane];
        int si = s;
        #pragma unroll
        for (int dd = 1; dd < 16; dd <<= 1) {
            int t2 = __shfl_up(si, dd);
            if (lane >= dd) si += t2;
        }
        wsum[lane] = si - s;
    }
    __syncthreads();
    {
        int o = loc[tid] + wsum[w];
        loc[tid] = o;
        lcur[tid] = o;
        // Reserve global span (padded line per range; 128 contenders/addr).
        base[tid] = (v > 0) ? atomicAdd(&cursor[tid * CSTRIDE], v) : 0;
    }
    __syncthreads();

    // Pass 2 (L2/L3-hot re-read): place edges range-sorted into LDS stage.
    // stage is an exact permutation of the chunk -> no overflow possible.
    for (int i = tid; i < CH2; i += 1024) {
        int2 d = dch[i];
        int2 s = sch[i];
        {
            unsigned r = (unsigned)d.x / RN;
            unsigned dl = (unsigned)d.x - r * RN;
            int p = atomicAdd(&lcur[r], 1);
            stage[p] = (int)((dl << 17) | (unsigned)s.x);
        }
        {
            unsigned r = (unsigned)d.y / RN;
            unsigned dl = (unsigned)d.y - r * RN;
            int p = atomicAdd(&lcur[r], 1);
            stage[p] = (int)((dl << 17) | (unsigned)s.y);
        }
    }
    __syncthreads();

    // Dump: wave w handles ranges [64w, 64w+64); each range's ~12-int span is
    // lane-contiguous in global (coalesced, ~1 line, this block only writer).
    for (int r = (w << 6); r < (w << 6) + 64; ++r) {
        int c = cnt[r];
        int b = base[r];
        int lo = loc[r];
        for (int j = lane; j < c; j += 64) {
            int slot = b + j;
            if (slot < CAP)
                bucket[(size_t)r * CAP + slot] = stage[lo + j];
        }
    }
}

// Layer 1 (exact round-8 version): LDS counting-sort of the range's edges to
// node order, 4-lane-per-node walk + distributed MLP. Dumps sorted CSR in
// place over the bucket region + offdeg for the layer-2 gather walk.
__global__ __launch_bounds__(512) void sage1_range(
        const int* __restrict__ bucket, const int* __restrict__ cursor,
        const float* __restrict__ x,
        const float* __restrict__ W_l1, const float* __restrict__ b_l1,
        const float* __restrict__ W_r1,
        const float* __restrict__ W_l2, const float* __restrict__ b_l2,
        const float* __restrict__ W_r2,
        int* __restrict__ csr, int* __restrict__ offdeg,
        float* __restrict__ g, float* __restrict__ out_rt) {
    __shared__ int raw[CAP];
    __shared__ int seg[CAP];
    __shared__ int scnt[128];
    __shared__ int soff[128];
    __shared__ int scur[128];
    __shared__ int wtot[2];
    __shared__ float sWl[HID_CH * IN_CH];
    __shared__ float sWr[HID_CH * IN_CH];
    __shared__ float sb[HID_CH];
    __shared__ float sWl2[OUT_CH * HID_CH];
    __shared__ float sWr2[OUT_CH * HID_CH];
    __shared__ float sb2[OUT_CH];

    int tid = threadIdx.x;
    for (int i = tid; i < HID_CH * IN_CH; i += 512) {
        sWl[i] = W_l1[i];
        sWr[i] = W_r1[i];
    }
    for (int i = tid; i < HID_CH; i += 512) sb[i] = b_l1[i];
    for (int i = tid; i < OUT_CH * HID_CH; i += 512) {
        sWl2[i] = W_l2[i];
        sWr2[i] = W_r2[i];
    }
    if (tid < OUT_CH) sb2[tid] = b_l2[tid];
    if (tid < 128) scnt[tid] = 0;

    int r = blockIdx.x;
    int len = cursor[r * CSTRIDE];
    if (len > CAP) len = CAP;
    const int* bin = bucket + (size_t)r * CAP;
    for (int j = tid; j < len; j += 512) raw[j] = bin[j];
    __syncthreads();

    for (int j = tid; j < len; j += 512) atomicAdd(&scnt[raw[j] >> 17], 1);
    __syncthreads();

    // Exclusive scan over 128 slots (RN=98 padded): per-wave shfl scan, 2 waves.
    int lane = tid & 63;
    if (tid < 128) {
        int v = scnt[tid];
        int incl = v;
        #pragma unroll
        for (int d = 1; d < 64; d <<= 1) {
            int t2 = __shfl_up(incl, d);
            if (lane >= d) incl += t2;
        }
        if (lane == 63) wtot[tid >> 6] = incl;
        soff[tid] = incl - v;
    }
    __syncthreads();
    if (tid < 128) {
        int o = soff[tid] + ((tid >= 64) ? wtot[0] : 0);
        soff[tid] = o;
        scur[tid] = o;
    }
    __syncthreads();

    for (int j = tid; j < len; j += 512) {
        int w = raw[j];
        int p = atomicAdd(&scur[w >> 17], 1);
        seg[p] = w & 0x1FFFF;
    }
    __syncthreads();

    // Dump node-sorted CSR in place over the bucket region (coalesced).
    int* cw = csr + (size_t)r * CAP;
    for (int j = tid; j < len; j += 512) cw[j] = seg[j];

    // Walk: 4 lanes per node, independent (pipelineable) LDS + global loads.
    int q = tid >> 2;
    int l = tid & 3;
    int node = r * RN + q;
    if (q < RN && node < N_NODES) {
        int o = soff[q];
        int dn = scnt[q];
        if (l == 0) offdeg[node] = o | (dn << 16);

        float acc[IN_CH];
        #pragma unroll
        for (int c = 0; c < IN_CH; c++) acc[c] = 0.0f;
        for (int j = o + l; j < o + dn; j += 4) {
            int s = seg[j];
            const float4* xs = (const float4*)(x + (size_t)s * IN_CH);
            float4 a = xs[0];
            float4 b = xs[1];
            acc[0] += a.x; acc[1] += a.y; acc[2] += a.z; acc[3] += a.w;
            acc[4] += b.x; acc[5] += b.y; acc[6] += b.z; acc[7] += b.w;
        }
        #pragma unroll
        for (int c = 0; c < IN_CH; c++) {
            acc[c] += __shfl_xor(acc[c], 1);
            acc[c] += __shfl_xor(acc[c], 2);
        }
        float inv = 1.0f / fmaxf((float)dn, 1.0f);
        float ag[IN_CH], xa[IN_CH];
        #pragma unroll
        for (int c = 0; c < IN_CH; c++) ag[c] = acc[c] * inv;
        const float4* xp = (const float4*)(x + (size_t)node * IN_CH);
        float4 x0 = xp[0], x1 = xp[1];
        xa[0] = x0.x; xa[1] = x0.y; xa[2] = x0.z; xa[3] = x0.w;
        xa[4] = x1.x; xa[5] = x1.y; xa[6] = x1.z; xa[7] = x1.w;

        // Distributed MLP: lane l handles hidden units [16l, 16l+16).
        float g0 = 0.f, g1 = 0.f, r0 = 0.f, r1 = 0.f;
        int k0 = l * 16;
        #pragma unroll 4
        for (int kk = k0; kk < k0 + 16; kk++) {
            float hk = sb[kk];
            #pragma unroll
            for (int c = 0; c < IN_CH; c++) {
                hk += sWl[kk * IN_CH + c] * ag[c];
                hk += sWr[kk * IN_CH + c] * xa[c];
            }
            hk = fmaxf(hk, 0.0f);   // ReLU (dropout identity in eval)
            g0 += sWl2[kk] * hk;
            g1 += sWl2[HID_CH + kk] * hk;
            r0 += sWr2[kk] * hk;
            r1 += sWr2[HID_CH + kk] * hk;
        }
        g0 += __shfl_xor(g0, 1); g0 += __shfl_xor(g0, 2);
        g1 += __shfl_xor(g1, 1); g1 += __shfl_xor(g1, 2);
        r0 += __shfl_xor(r0, 1); r0 += __shfl_xor(r0, 2);
        r1 += __shfl_xor(r1, 1); r1 += __shfl_xor(r1, 2);
        if (l == 0) {
            g[(size_t)node * 2 + 0] = g0;
            g[(size_t)node * 2 + 1] = g1;
            float2 rt;
            rt.x = r0 + sb2[0];
            rt.y = r1 + sb2[1];
            *(float2*)(out_rt + (size_t)node * 2) = rt;
        }
    }
}

// Layer 2 (round-0 walk): 4 lanes/node read the node's contiguous CSR span
// from global (L1/L2-hot window per range), gather g[src], shfl-reduce;
// out = sum/max(dn,1) + rt. No LDS, no barriers, no atomics.
__global__ __launch_bounds__(256) void sage2_kernel(
        const int* __restrict__ csr, const int* __restrict__ offdeg,
        const float* __restrict__ g, float* __restrict__ out) {
    int t = blockIdx.x * blockDim.x + threadIdx.x;
    int node = t >> 2;
    int l = t & 3;
    if (node >= N_NODES) return;
    int r = node / RN;
    int od = offdeg[node];
    int o = od & 0xFFFF;
    int dn = od >> 16;
    const int* seg = csr + (size_t)r * CAP;
    float a0 = 0.f, a1 = 0.f;
    for (int j = o + l; j < o + dn; j += 4) {
        int s = seg[j];
        float2 gv = *(const float2*)(g + (size_t)s * 2);
        a0 += gv.x;
        a1 += gv.y;
    }
    a0 += __shfl_xor(a0, 1); a0 += __shfl_xor(a0, 2);
    a1 += __shfl_xor(a1, 1); a1 += __shfl_xor(a1, 2);
    if (l == 0) {
        float inv = 1.0f / fmaxf((float)dn, 1.0f);
        float2 rt = *(const float2*)(out + (size_t)node * 2);
        float2 ov;
        ov.x = a0 * inv + rt.x;
        ov.y = a1 * inv + rt.y;
        *(float2*)(out + (size_t)node * 2) = ov;
    }
}

extern "C" void kernel_launch(void* const* d_in, const int* in_sizes, int n_in,
                              void* d_out, int out_size, void* d_ws, size_t ws_size,
                              hipStream_t stream) {
    const float* x    = (const float*)d_in[0];
    const int*   ei   = (const int*)d_in[1];   // [2, N_EDGES] int32 per harness
    const float* W_l1 = (const float*)d_in[2];
    const float* b_l1 = (const float*)d_in[3];
    const float* W_r1 = (const float*)d_in[4];
    const float* W_l2 = (const float*)d_in[5];
    const float* b_l2 = (const float*)d_in[6];
    const float* W_r2 = (const float*)d_in[7];
    float* out = (float*)d_out;

    const int* src = ei;
    const int* dst = ei + N_EDGES;

    int*   cursor = (int*)d_ws;
    int*   bucket = (int*)d_ws + WS_BUCKET;
    int*   offdeg = (int*)d_ws + WS_OFFDEG;
    float* g      = (float*)d_ws + WS_G;

    hipMemsetAsync(cursor, 0, R2 * CSTRIDE * sizeof(int), stream);

    bucket_sort<<<NB, 1024, 0, stream>>>(src, dst, cursor, bucket);
    sage1_range<<<R2, 512, 0, stream>>>(bucket, cursor, x,
                                        W_l1, b_l1, W_r1, W_l2, b_l2, W_r2,
                                        bucket /*csr in place*/, offdeg, g, out);
    sage2_kernel<<<(4 * N_NODES + 255) / 256, 256, 0, stream>>>(bucket, offdeg, g, out);
}